// Round 13
// baseline (9922.717 us; speedup 1.0000x reference)
//
#include <hip/hip_runtime.h>
#include <stdint.h>

#define B_ 32
#define T_ 128
#define S_ 256
#define D_ 1024
#define V_ 10000

typedef unsigned short u16;
typedef unsigned char u8;
typedef unsigned long long u64;
typedef __attribute__((ext_vector_type(8))) short bf16x8;   // 8 bf16 in 4 VGPRs
typedef __attribute__((ext_vector_type(4))) float f32x4;
typedef __attribute__((ext_vector_type(4))) unsigned int u32x4;

__device__ __forceinline__ float bf2f(u16 u){ union { unsigned int i; float f; } v; v.i = ((unsigned int)u)<<16; return v.f; }
__device__ __forceinline__ u16 f2bf(float f){ union { float ff; unsigned int i; } v; v.ff = f; unsigned int x = v.i; return (u16)((x + 0x7fffu + ((x>>16)&1u))>>16); }
// exact branch-free e4m3 decode (incl. subnormals)
__device__ __forceinline__ float fp82f(unsigned int x){
  union { unsigned int i; float f; } v;
  v.i = ((x & 0x80u) << 24) | ((x & 0x7Fu) << 20);
  return v.f * 0x1.0p+120f;
}
// e4m3 encode with RNE (clamped to +-240)
__device__ __forceinline__ u8 f2fp8(float f){
  union { float ff; unsigned int i; } v;
  v.ff = fminf(fmaxf(f, -240.f), 240.f) * 0x1.0p-120f;
  unsigned int s = (v.i >> 24) & 0x80u;
  unsigned int u = v.i & 0x7FFFFFFFu;
  u += ((u >> 20) & 1u) + 0x7FFFFu;
  return (u8)(s | ((u >> 20) & 0x7Fu));
}
// fast inf-safe activations
__device__ __forceinline__ float ftanh(float x){
  float e = __expf(2.f*x);
  return __builtin_fmaf(-2.f, __builtin_amdgcn_rcpf(1.f+e), 1.f);
}
__device__ __forceinline__ float sigm(float x){
  return __builtin_amdgcn_rcpf(1.f + __expf(-x));
}

// ---------------- prep kernels ----------------
__global__ void k_cast(const float* __restrict__ in, u16* __restrict__ out, long n){
  for (long i = (long)blockIdx.x*blockDim.x + threadIdx.x; i < n; i += (long)gridDim.x*blockDim.x)
    out[i] = f2bf(in[i]);
}

__global__ void k_cast8(const float* __restrict__ in, u8* __restrict__ out, long n){
  for (long i = (long)blockIdx.x*blockDim.x + threadIdx.x; i < n; i += (long)gridDim.x*blockDim.x)
    out[i] = f2fp8(in[i]);
}

__global__ void k_w1cat(const float* __restrict__ wih1, const float* __restrict__ whh1, u16* __restrict__ out){
  const long n = (long)4096*2048;
  for (long i = (long)blockIdx.x*blockDim.x + threadIdx.x; i < n; i += (long)gridDim.x*blockDim.x){
    int row = (int)(i >> 11), k = (int)(i & 2047);
    float v = (k < D_) ? wih1[(size_t)row*D_ + k] : whh1[(size_t)row*D_ + (k - D_)];
    out[i] = f2bf(v);
  }
}

__global__ void k_bias(const float* __restrict__ bih, const float* __restrict__ bhh,
                       const float* __restrict__ bcv, const float* __restrict__ abias,
                       const float* __restrict__ Wcv, const float* __restrict__ fcw,
                       float* __restrict__ bias0, float* __restrict__ bias1,
                       float* __restrict__ biasE, float* __restrict__ convw){
  int i = blockIdx.x*blockDim.x + threadIdx.x;
  if (i < 4096){ bias0[i] = bih[i]+bhh[i]; bias1[i] = bih[4096+i]+bhh[4096+i]; }
  if (i < 1024){
    biasE[i] = bcv[i]+abias[i];
    convw[i*4+0]=Wcv[i*3+0]; convw[i*4+1]=Wcv[i*3+1]; convw[i*4+2]=Wcv[i*3+2]; convw[i*4+3]=fcw[i];
  }
}

__global__ void k_gather(const float* __restrict__ emb, const int* __restrict__ tgt, u16* __restrict__ embA){
  int row = blockIdx.x;            // row = t*32 + b
  int t = row >> 5, b = row & 31;
  int e = tgt[b*T_ + t];
  const float* src = emb + (size_t)e*D_;
  u16* dst = embA + (size_t)row*D_;
  for (int d = threadIdx.x; d < D_; d += 256) dst[d] = f2bf(src[d]);
}

// ---------------- big MFMA GEMM: C = A(M x K, lda) @ B(N x K)^T (+bias)(+act) ----------------
__device__ __forceinline__ void gld_lds(const u16* g, u16* l){
  __builtin_amdgcn_global_load_lds((const __attribute__((address_space(1))) unsigned int*)g,
                                   (__attribute__((address_space(3))) unsigned int*)l, 16, 0, 0);
}

template<int OUT_MODE, bool SWIZ>   // OUT_MODE: 0 f32, 1 bf16, 2 tanh->bf16, 3 fp8 ; SWIZ: row(t*32+b)->(b*128+t)
__global__ __launch_bounds__(256) void k_gemm128(const u16* __restrict__ Am, const u16* __restrict__ Bm,
      const float* __restrict__ bias, void* __restrict__ Cout, int M, int N, int K, int lda, int ldc)
{
  __shared__ u16 As[128*32];
  __shared__ u16 Bs[128*32];
  int bm = blockIdx.y*128, bn = blockIdx.x*128;
  int tid = threadIdx.x;
  int wv = tid>>6, lane = tid&63;
  int wm = (wv>>1)*64, wn = (wv&1)*64;
  int r = lane&15, kh = lane>>4;
  f32x4 zero = {0.f,0.f,0.f,0.f};
  f32x4 acc[4][4];
  #pragma unroll
  for (int mi=0;mi<4;mi++)
    #pragma unroll
    for (int ni=0;ni<4;ni++) acc[mi][ni] = zero;

  for (int k0 = 0; k0 < K; k0 += 32){
    #pragma unroll
    for (int i=0;i<2;i++){
      int c = tid + i*256;
      int row = c>>2, ko = (c&3)*8;
      int ga = bm+row; if (ga > M-1) ga = M-1;
      gld_lds(Am + (size_t)ga*lda + k0 + ko, As + c*8);
      int gb = bn+row; if (gb > N-1) gb = N-1;
      gld_lds(Bm + (size_t)gb*K + k0 + ko, Bs + c*8);
    }
    __syncthreads();
    bf16x8 af[4], bfv[4];
    #pragma unroll
    for (int mi=0;mi<4;mi++) af[mi]  = *(const bf16x8*)(As + (wm+mi*16+r)*32 + kh*8);
    #pragma unroll
    for (int ni=0;ni<4;ni++) bfv[ni] = *(const bf16x8*)(Bs + (wn+ni*16+r)*32 + kh*8);
    #pragma unroll
    for (int mi=0;mi<4;mi++)
      #pragma unroll
      for (int ni=0;ni<4;ni++)
        acc[mi][ni] = __builtin_amdgcn_mfma_f32_16x16x32_bf16(af[mi], bfv[ni], acc[mi][ni], 0,0,0);
    __syncthreads();
  }
  #pragma unroll
  for (int mi=0;mi<4;mi++)
    #pragma unroll
    for (int ni=0;ni<4;ni++)
      #pragma unroll
      for (int rr=0;rr<4;rr++){
        int grow = bm+wm+mi*16+kh*4+rr;
        int gcol = bn+wn+ni*16+r;
        if (grow < M && gcol < N){
          float v = acc[mi][ni][rr];
          if (bias) v += bias[gcol];
          size_t orow = SWIZ ? (size_t)((grow&31)*T_ + (grow>>5)) : (size_t)grow;
          if (OUT_MODE==0)      ((float*)Cout)[orow*(size_t)ldc + gcol] = v;
          else if (OUT_MODE==1) ((u16*)Cout)[orow*(size_t)ldc + gcol] = f2bf(v);
          else if (OUT_MODE==2) ((u16*)Cout)[orow*(size_t)ldc + gcol] = f2bf(ftanh(v));
          else                  ((u8*)Cout)[orow*(size_t)ldc + gcol] = f2fp8(v);
        }
      }
}

// ---------------- hierarchical fence-free barrier (256 blocks) ----------------
__device__ __forceinline__ void xcd_barrier(int* barL, int it){
  asm volatile("s_waitcnt vmcnt(0)" ::: "memory");
  __syncthreads();
  if (threadIdx.x==0){
    int grp = blockIdx.x & 7;
    int* gcnt = barL + grp*32;
    int* root = barL + 256;
    int* rel  = barL + 320 + grp*32;
    int v = __hip_atomic_fetch_add(gcnt, 1, __ATOMIC_RELAXED, __HIP_MEMORY_SCOPE_AGENT);
    if (v == 32*(it+1) - 1){
      int rv = __hip_atomic_fetch_add(root, 1, __ATOMIC_RELAXED, __HIP_MEMORY_SCOPE_AGENT);
      if (rv == 8*(it+1) - 1){
        #pragma unroll
        for (int g2=0; g2<8; ++g2)
          __hip_atomic_store(barL + 320 + g2*32, it+1, __ATOMIC_RELAXED, __HIP_MEMORY_SCOPE_AGENT);
      }
    }
    while (__hip_atomic_load(rel, __ATOMIC_RELAXED, __HIP_MEMORY_SCOPE_AGENT) < it+1)
      __builtin_amdgcn_s_sleep(2);
  }
  __syncthreads();
}

// ---------------- fused persistent decoder, WAVE-SPECIALIZED ----------------
// 256 blocks x 512 thr. Waves 0-3: LSTM (G0/G1/qp MFMA + cells). Waves 4-7: attention.
// Pipeline at iter i: G0(i) | G1(i-1) | qp(i-2) | energy(i-3) | softmax+context(i-4).
// 4 unconditional __syncthreads align the groups; work between syncs overlaps on SIMDs.
__global__ __launch_bounds__(512) void k_fused(const u16* __restrict__ Whh0, const u16* __restrict__ W1cat,
    const u16* __restrict__ Wqm, const u16* __restrict__ X0, const float* __restrict__ bias1,
    const u8* __restrict__ vp8, const u8* __restrict__ enc8, const float* __restrict__ convw,
    u16* __restrict__ Hh, u16* __restrict__ qps, float* __restrict__ eng,
    u16* __restrict__ qcat, int* __restrict__ barL)
{
  __shared__ u16 W0s[16*1024];     // 32 KB
  __shared__ u16 W1s[16*2048];     // 64 KB
  __shared__ u16 Wqs[4*1024];      // 8 KB
  __shared__ float gl0[4*512];     // 8 KB (4 LSTM-wave partials)
  __shared__ float gl1[4*512];     // 8 KB
  __shared__ float glq[2*128];     // 1 KB (waves 2-3)
  __shared__ float aw[256];
  __shared__ float red[8];
  __shared__ float cred[256];
  int bid = blockIdx.x, tid = threadIdx.x;
  int w = tid>>6, lane = tid&63, r = lane&15, kh = lane>>4;
  int batt = bid>>3, part = bid&7;
  bool isATT = (w >= 4);
  // ---- stage weight slices into LDS once (all waves) ----
  for (int ci = tid; ci < 2048; ci += 512){
    int row = ci>>7, c = ci&127;
    int grow = (row>>2)*1024 + bid*4 + (row&3);
    bf16x8 v = *(const bf16x8*)(Whh0 + (size_t)grow*1024 + c*8);
    *(bf16x8*)(W0s + (size_t)(((row<<7) + (c ^ (row&7)))*8)) = v;
  }
  for (int ci = tid; ci < 4096; ci += 512){
    int row = ci>>8, c = ci&255;
    int grow = (row>>2)*1024 + bid*4 + (row&3);
    bf16x8 v = *(const bf16x8*)(W1cat + (size_t)grow*2048 + c*8);
    *(bf16x8*)(W1s + (size_t)(((row<<8) + (c ^ (row&7)))*8)) = v;
  }
  {
    int row = tid>>7, c = tid&127;
    bf16x8 v = *(const bf16x8*)(Wqm + (size_t)(bid*4+row)*1024 + c*8);
    *(bf16x8*)(Wqs + (size_t)(((row<<7) + (c ^ (row&7)))*8)) = v;
  }
  if (isATT){ int s = tid-256; aw[s] = 0.f; }
  __syncthreads();
  // per-role persistent state
  float c0reg = 0.f, c1reg = 0.f;
  int cb = tid>>2, cj = tid&3;          // cell thread (tid<128)
  int col = bid*4 + cj;
  float b1i=0.f, b1f=0.f, b1g=0.f, b1o=0.f;
  if (tid < 128){ b1i=bias1[col]; b1f=bias1[1024+col]; b1g=bias1[2048+col]; b1o=bias1[3072+col]; }
  // ATT persistent: conv weights for energy (d0 = lane*16)
  int d0 = lane*16;
  f32x4 cw[16];
  if (isATT){
    #pragma unroll
    for (int j=0;j<16;j++) cw[j] = *(const f32x4*)(convw + (size_t)(d0+j)*4);
  }
  for (int i = 0; i <= T_+3; ++i){
    const u16* Hprev = Hh + (size_t)i*65536;       // slot i-1
    u16* Hcur = (u16*)Hh + (size_t)(i+1)*65536;    // slot i
    bool doG0 = (i < T_);
    bool doG1 = (i >= 1 && i <= T_);
    bool loadG1 = (i >= 1 && i <= T_+1);
    bool doQP = (i >= 2 && i <= T_+1);
    bool doEN = (i >= 3 && i <= T_+2);
    bool doSM = (i >= 4);
    // LSTM regs
    bf16x8 a_g0[2][8], a_g1a[2][8], a_g1b[2][8];
    float x_gi=0.f, x_gf=0.f, x_gg=0.f, x_go=0.f;
    // ATT regs
    float e_val=0.f, ex=0.f;
    // ======== phase A ========
    if (!isATT){
      if (doG0){
        const u16* a0 = Hprev + (size_t)r*2048 + w*256 + kh*8;
        const u16* a1 = Hprev + (size_t)(16+r)*2048 + w*256 + kh*8;
        #pragma unroll
        for (int kk=0;kk<8;kk++){ a_g0[0][kk] = *(const bf16x8*)(a0 + kk*32);
                                  a_g0[1][kk] = *(const bf16x8*)(a1 + kk*32); }
      }
      if (loadG1){
        const u16* a0 = Hprev + (size_t)r*2048 + w*512 + kh*8;
        const u16* a1 = Hprev + (size_t)(16+r)*2048 + w*512 + kh*8;
        #pragma unroll
        for (int kk=0;kk<8;kk++){ a_g1a[0][kk] = *(const bf16x8*)(a0 + kk*32);
                                  a_g1a[1][kk] = *(const bf16x8*)(a1 + kk*32); }
        #pragma unroll
        for (int kk=0;kk<8;kk++){ a_g1b[0][kk] = *(const bf16x8*)(a0 + 256 + kk*32);
                                  a_g1b[1][kk] = *(const bf16x8*)(a1 + 256 + kk*32); }
      }
      if (doG0 && tid < 128){
        const u16* xr = X0 + ((size_t)i*32 + cb)*4096 + col;
        x_gi = bf2f(xr[0]); x_gf = bf2f(xr[1024]); x_gg = bf2f(xr[2048]); x_go = bf2f(xr[3072]);
      }
    } else {
      if (doSM){
        int t = i-4;
        float* ebuf = eng + (t&1)*8192 + batt*256;
        int s = tid-256;
        e_val = __hip_atomic_load(ebuf + s, __ATOMIC_RELAXED, __HIP_MEMORY_SCOPE_AGENT);
        float m = e_val;
        #pragma unroll
        for (int o=32;o;o>>=1) m = fmaxf(m, __shfl_xor(m,o));
        if (lane==0) red[w-4] = m;
      }
    }
    __syncthreads();   // S1
    // ======== phase B ========
    f32x4 acc00={0.f,0.f,0.f,0.f}, acc01={0.f,0.f,0.f,0.f};
    f32x4 acc10={0.f,0.f,0.f,0.f}, acc11={0.f,0.f,0.f,0.f};
    f32x4 accq0={0.f,0.f,0.f,0.f}, accq1={0.f,0.f,0.f,0.f};
    if (!isATT){
      if (doG0){
        #pragma unroll
        for (int kk=0;kk<8;kk++){
          int c = (w<<5) + (kk<<2) + kh;
          bf16x8 bv = *(const bf16x8*)(W0s + (size_t)((((int)r<<7) + (c ^ (r&7)))*8));
          acc00 = __builtin_amdgcn_mfma_f32_16x16x32_bf16(a_g0[0][kk], bv, acc00, 0,0,0);
          acc01 = __builtin_amdgcn_mfma_f32_16x16x32_bf16(a_g0[1][kk], bv, acc01, 0,0,0);
        }
      }
      if (doG1){
        #pragma unroll
        for (int kk=0;kk<8;kk++){
          int c = (w<<6) + (kk<<2) + kh;
          bf16x8 bv = *(const bf16x8*)(W1s + (size_t)((((int)r<<8) + (c ^ (r&7)))*8));
          acc10 = __builtin_amdgcn_mfma_f32_16x16x32_bf16(a_g1a[0][kk], bv, acc10, 0,0,0);
          acc11 = __builtin_amdgcn_mfma_f32_16x16x32_bf16(a_g1a[1][kk], bv, acc11, 0,0,0);
        }
      }
    } else {
      if (doSM){
        float mx = fmaxf(fmaxf(red[0],red[1]),fmaxf(red[2],red[3]));
        ex = __expf(e_val - mx);
        float sl = ex;
        #pragma unroll
        for (int o=32;o;o>>=1) sl += __shfl_xor(sl,o);
        if (lane==0) red[4+(w-4)] = sl;
      }
    }
    __syncthreads();   // S2
    // ======== phase C ========
    if (!isATT){
      if (doG1){
        #pragma unroll
        for (int kk=0;kk<8;kk++){
          int c = (w<<6) + 32 + (kk<<2) + kh;
          bf16x8 bv = *(const bf16x8*)(W1s + (size_t)((((int)r<<8) + (c ^ (r&7)))*8));
          acc10 = __builtin_amdgcn_mfma_f32_16x16x32_bf16(a_g1b[0][kk], bv, acc10, 0,0,0);
          acc11 = __builtin_amdgcn_mfma_f32_16x16x32_bf16(a_g1b[1][kk], bv, acc11, 0,0,0);
        }
      }
      if (doQP && w >= 2){   // h1 lives in waves 2-3's a_g1 regs
        int qrw = r & 3;
        #pragma unroll
        for (int kk=0;kk<8;kk++){
          int c = ((w-2)<<6) + (kk<<2) + kh;
          bf16x8 bv = *(const bf16x8*)(Wqs + (size_t)(((qrw<<7) + (c ^ (qrw&7)))*8));
          accq0 = __builtin_amdgcn_mfma_f32_16x16x32_bf16(a_g1a[0][kk], bv, accq0, 0,0,0);
          accq1 = __builtin_amdgcn_mfma_f32_16x16x32_bf16(a_g1a[1][kk], bv, accq1, 0,0,0);
        }
        #pragma unroll
        for (int kk=0;kk<8;kk++){
          int c = ((w-2)<<6) + 32 + (kk<<2) + kh;
          bf16x8 bv = *(const bf16x8*)(Wqs + (size_t)(((qrw<<7) + (c ^ (qrw&7)))*8));
          accq0 = __builtin_amdgcn_mfma_f32_16x16x32_bf16(a_g1b[0][kk], bv, accq0, 0,0,0);
          accq1 = __builtin_amdgcn_mfma_f32_16x16x32_bf16(a_g1b[1][kk], bv, accq1, 0,0,0);
        }
      }
      // write partials
      #pragma unroll
      for (int rr=0;rr<4;rr++){
        gl0[w*512 + (kh*4+rr)*16 + r]    = acc00[rr];
        gl0[w*512 + (16+kh*4+rr)*16 + r] = acc01[rr];
        gl1[w*512 + (kh*4+rr)*16 + r]    = acc10[rr];
        gl1[w*512 + (16+kh*4+rr)*16 + r] = acc11[rr];
      }
      if (doQP && w >= 2 && r < 4){
        #pragma unroll
        for (int rr=0;rr<4;rr++){
          glq[(w-2)*128 + (kh*4+rr)*4 + r]    = accq0[rr];
          glq[(w-2)*128 + (16+kh*4+rr)*4 + r] = accq1[rr];
        }
      }
    } else {
      if (doSM){
        float st = red[4]+red[5]+red[6]+red[7];
        aw[tid-256] = ex * __builtin_amdgcn_rcpf(st);
      }
    }
    __syncthreads();   // S3
    // ======== phase D part 1 ========
    if (!isATT){
      if (tid < 128){
        if (doG0){
          float gi=x_gi, gf=x_gf, gg=x_gg, go=x_go;
          #pragma unroll
          for (int ww=0;ww<4;ww++){
            const float* gp = gl0 + ww*512 + cb*16 + cj;
            gi += gp[0]; gf += gp[4]; gg += gp[8]; go += gp[12];
          }
          float cn = sigm(gf)*c0reg + sigm(gi)*ftanh(gg);
          float hn = sigm(go)*ftanh(cn); c0reg = cn;
          __hip_atomic_store(Hcur + (size_t)cb*2048 + col, f2bf(hn),
                             __ATOMIC_RELAXED, __HIP_MEMORY_SCOPE_AGENT);
        }
        if (doG1){
          float gi=b1i, gf=b1f, gg=b1g, go=b1o;
          #pragma unroll
          for (int ww=0;ww<4;ww++){
            const float* gp = gl1 + ww*512 + cb*16 + cj;
            gi += gp[0]; gf += gp[4]; gg += gp[8]; go += gp[12];
          }
          float cn = sigm(gf)*c1reg + sigm(gi)*ftanh(gg);
          float hn = sigm(go)*ftanh(cn); c1reg = cn;
          u16 hb = f2bf(hn);
          __hip_atomic_store(Hcur + (size_t)cb*2048 + 1024 + col, hb,
                             __ATOMIC_RELAXED, __HIP_MEMORY_SCOPE_AGENT);
          qcat[((size_t)(i-1)*32 + cb)*2048 + col] = hb;   // q, normal store
        }
        if (doQP){
          float hq = glq[cb*4+cj] + glq[128 + cb*4+cj];
          __hip_atomic_store(qps + ((size_t)(i-2)*32 + cb)*1024 + col, f2bf(hq),
                             __ATOMIC_RELAXED, __HIP_MEMORY_SCOPE_AGENT);
        }
      }
    } else {
      if (doSM){   // context partials: 256 ATT threads, 2-way s-split, 128 d-cols
        int ct = tid-256, sq = ct>>7, dt = ct&127;
        const u8* ep = enc8 + (size_t)(batt*256 + sq*128)*1024 + part*128 + dt;
        float a0=0.f,a1=0.f,a2=0.f,a3=0.f;
        #pragma unroll 4
        for (int s2=0;s2<128;s2+=4){
          a0 += aw[sq*128+s2]   * fp82f(ep[(size_t)(s2)  *1024]);
          a1 += aw[sq*128+s2+1] * fp82f(ep[(size_t)(s2+1)*1024]);
          a2 += aw[sq*128+s2+2] * fp82f(ep[(size_t)(s2+2)*1024]);
          a3 += aw[sq*128+s2+3] * fp82f(ep[(size_t)(s2+3)*1024]);
        }
        cred[ct] = a0+a1+a2+a3;
      }
    }
    __syncthreads();   // S4
    // ======== phase D part 2 ========
    if (isATT){
      if (doSM){
        int ct = tid-256, t = i-4;
        if (ct < 128)
          qcat[((size_t)t*32 + batt)*2048 + 1024 + part*128 + ct] =
            f2bf(cred[ct] + cred[128+ct]);
      }
      if (doEN){
        int t = i-3;
        float* ebuf = eng + (t&1)*8192 + batt*256;
        const u16* qrow = qps + ((size_t)t*32 + batt)*1024 + d0;
        bf16x8 q0 = *(const bf16x8*)qrow, q1 = *(const bf16x8*)(qrow+8);
        float qf[16];
        #pragma unroll
        for (int j=0;j<16;j++) qf[j] = bf2f((u16)(j<8 ? q0[j] : q1[j-8]));
        #pragma unroll
        for (int ss=0; ss<8; ++ss){
          int s = part*32 + (w-4)*8 + ss;
          float am = (s>0)   ? aw[s-1] : 0.f;
          float ac =           aw[s];
          float av = (s<255) ? aw[s+1] : 0.f;
          const u32x4 vv4 = *(const u32x4*)(vp8 + ((size_t)(batt*256+s))*1024 + d0);
          float sum = 0.f;
          #pragma unroll
          for (int j=0;j<16;j++){
            unsigned int word = vv4[j>>2];
            float vv = fp82f((word >> ((j&3)*8)) & 0xFFu);
            float x = qf[j] + vv + am*cw[j][0] + ac*cw[j][1] + av*cw[j][2];
            sum += ftanh(x)*cw[j][3];
          }
          #pragma unroll
          for (int o=32;o;o>>=1) sum += __shfl_xor(sum, o);
          if (lane==0)
            __hip_atomic_store(ebuf + s, sum, __ATOMIC_RELAXED, __HIP_MEMORY_SCOPE_AGENT);
        }
      }
    }
    if (i < T_+3) xcd_barrier(barL, i);
  }
}

// in-place log_softmax over V per row of out (register-cached)
__global__ __launch_bounds__(256) void k_logsm(float* __restrict__ out){
  int row = blockIdx.x, tid = threadIdx.x;
  float* p = out + (size_t)row*V_;
  __shared__ float red[4];
  float pv[40];
  int nv = 0;
  float mx = -3.0e38f;
  for (int v=tid; v<V_; v+=256){ float x = p[v]; pv[nv++] = x; mx = fmaxf(mx, x); }
  #pragma unroll
  for (int o=32;o;o>>=1) mx = fmaxf(mx, __shfl_xor(mx,o));
  if ((tid&63)==0) red[tid>>6]=mx;
  __syncthreads();
  mx = fmaxf(fmaxf(red[0],red[1]),fmaxf(red[2],red[3]));
  __syncthreads();
  float s = 0.f;
  for (int i=0;i<nv;i++) s += __expf(pv[i]-mx);
  #pragma unroll
  for (int o=32;o;o>>=1) s += __shfl_xor(s,o);
  if ((tid&63)==0) red[tid>>6]=s;
  __syncthreads();
  float lz = mx + __logf(red[0]+red[1]+red[2]+red[3]);
  { int i=0; for (int v=tid; v<V_; v+=256) p[v] = pv[i++] - lz; }
}

// ---------------- host ----------------
extern "C" void kernel_launch(void* const* d_in, const int* in_sizes, int n_in,
                              void* d_out, int out_size, void* d_ws, size_t ws_size,
                              hipStream_t stream)
{
  const float* enc   = (const float*)d_in[0];
  const int*   tgt   = (const int*)  d_in[1];
  const float* emb   = (const float*)d_in[2];
  const float* Wih   = (const float*)d_in[3];
  const float* Whh   = (const float*)d_in[4];
  const float* bih   = (const float*)d_in[5];
  const float* bhh   = (const float*)d_in[6];
  const float* Wcv   = (const float*)d_in[7];
  const float* bcv   = (const float*)d_in[8];
  const float* Wq    = (const float*)d_in[9];
  const float* Wvm   = (const float*)d_in[10];
  const float* abias = (const float*)d_in[11];
  const float* fcw   = (const float*)d_in[12];
  // d_in[13] fc_attn_b: softmax-invariant, unused
  const float* fc1w  = (const float*)d_in[14];
  const float* fc1b  = (const float*)d_in[15];
  const float* fc2w  = (const float*)d_in[16];
  const float* fc2b  = (const float*)d_in[17];
  float* out = (float*)d_out;

  char* base = (char*)d_ws; size_t off = 0;
  auto A = [&](size_t nbytes)->char*{ char* q = base + off; off += (nbytes + 255) & ~(size_t)255; return q; };
  u16* enc_bf  = (u16*)A(8388608ull*2);
  u16* Wv_bf   = (u16*)A(1048576ull*2);
  u16* Wih0_bf = (u16*)A(4194304ull*2);
  u16* W1cat   = (u16*)A(8388608ull*2);
  u16* Whh0_bf = (u16*)A(4194304ull*2);
  u16* Wq_bf   = (u16*)A(1048576ull*2);
  u16* fc1w_bf = (u16*)A(2097152ull*2);
  u16* fc2w_bf = (u16*)A(10240000ull*2);  // ALSO aliased as Hh during the fused loop
  u16* embA    = (u16*)A(4194304ull*2);   // reused: X0-GEMM A -> hid
  u16* X0      = (u16*)A(16777216ull*2);  // (T*32, 4096) bf16, includes bias0
  u8*  vp8     = (u8*)A(8388608ull);      // fp8(vproj + bconv + attn_bias)  [1 MB/XCD resident]
  u8*  enc8    = (u8*)A(8388608ull);      // fp8(encoder_outputs)            [1 MB/XCD resident]
  u16* qcat    = (u16*)A(8388608ull*2);   // (T*32, 2048) = [q | context]
  u16* qps     = (u16*)A(4194304ull*2);   // FRESH (T*32, 1024) bf16 qp slots
  float* bias0 = (float*)A(4096*4);
  float* bias1 = (float*)A(4096*4);
  float* biasE = (float*)A(1024*4);
  float* convw = (float*)A(4096*4);       // [d][{Wc0,Wc1,Wc2,fcw}]
  float* eng   = (float*)A(2*8192*4);     // attn energy double buffer
  int* barL    = (int*)A(4096);           // hierarchical barrier, 128B-padded lines
  u16* Hh      = fc2w_bf;                 // 130 slots x (32x2048) bf16 = 17.04 MB <= 20.48 MB
  u16* hid     = embA;

  // zero h-history slots -1 and 0 + barrier (re-done on every graph replay)
  hipMemsetAsync(Hh, 0, 2*65536*2, stream);
  hipMemsetAsync(barL, 0, 4096, stream);

  // prep: casts (fc2w cast DEFERRED until after the fused loop; its buffer holds Hh now)
  k_cast<<<2048,256,0,stream>>>(enc,  enc_bf,  8388608);
  k_cast8<<<2048,256,0,stream>>>(enc, enc8,    8388608);
  k_cast<<<1024,256,0,stream>>>(Wih,  Wih0_bf, 4194304);
  k_cast<<<1024,256,0,stream>>>(Whh,  Whh0_bf, 4194304);
  k_cast<<<512,256,0,stream>>>(Wq,    Wq_bf,   1048576);
  k_cast<<<512,256,0,stream>>>(Wvm,   Wv_bf,   1048576);
  k_cast<<<512,256,0,stream>>>(fc1w,  fc1w_bf, 2097152);
  k_w1cat<<<2048,256,0,stream>>>(Wih + 4194304, Whh + 4194304, W1cat);
  k_bias<<<16,256,0,stream>>>(bih, bhh, bcv, abias, Wcv, fcw, bias0, bias1, biasE, convw);
  k_gather<<<4096,256,0,stream>>>(emb, tgt, embA);

  // vp8 = fp8(enc @ Wv^T + (bconv + attn_bias))   (8192 x 1024 x 1024)
  k_gemm128<3,false><<<dim3(8,64),256,0,stream>>>(enc_bf, Wv_bf, biasE, vp8, 8192, 1024, 1024, 1024, 1024);
  // X0 = bf16(emb[targets] @ W_ih0^T + (b_ih0+b_hh0))  (4096 x 4096 x 1024)
  k_gemm128<1,false><<<dim3(32,32),256,0,stream>>>(embA, Wih0_bf, bias0, X0, 4096, 4096, 1024, 1024, 4096);

  // ---- fused persistent decoder loop (wave-specialized, 1 barrier/iter) ----
  {
    const u16* a0 = Whh0_bf; const u16* a1 = W1cat; const u16* a2 = Wq_bf; const u16* a3 = X0;
    const float* a4 = bias1; const u8* a5 = vp8; const u8* a6 = enc8; const float* a7 = convw;
    u16* a8 = Hh; u16* a9 = qps; float* a10 = eng; u16* a11 = qcat; int* a12 = barL;
    void* args[] = {(void*)&a0,(void*)&a1,(void*)&a2,(void*)&a3,(void*)&a4,(void*)&a5,(void*)&a6,
                    (void*)&a7,(void*)&a8,(void*)&a9,(void*)&a10,(void*)&a11,(void*)&a12};
    hipError_t e = hipLaunchCooperativeKernel((const void*)k_fused, dim3(256), dim3(512), args, 0, stream);
    if (e != hipSuccess)
      k_fused<<<dim3(256),dim3(512),0,stream>>>(a0,a1,a2,a3,a4,a5,a6,a7,a8,a9,a10,a11,a12);
  }

  // hid = tanh(qcat @ fc1w^T + fc1b)   (4096 x 1024 x 2048)
  k_gemm128<2,false><<<dim3(8,32),256,0,stream>>>(qcat, fc1w_bf, fc1b, hid, 4096, 1024, 2048, 2048, 1024);
  // fc2 weight cast (deferred; Hh no longer needed)
  k_cast<<<2048,256,0,stream>>>(fc2w, fc2w_bf, 10240000);
  // logits = hid @ fc2w^T + fc2b -> out[b][t][v]  (4096 x 10000 x 1024, row swizzle (t,b)->(b,t))
  k_gemm128<0,true><<<dim3(79,32),256,0,stream>>>(hid, fc2w_bf, fc2b, out, 4096, V_, 1024, 1024, V_);
  // in-place log_softmax over V
  k_logsm<<<4096,256,0,stream>>>(out);
}

// Round 14
// 2808.765 us; speedup vs baseline: 3.5328x; 3.5328x over previous
//
#include <hip/hip_runtime.h>
#include <stdint.h>

#define B_ 32
#define T_ 128
#define S_ 256
#define D_ 1024
#define V_ 10000

typedef unsigned short u16;
typedef unsigned long long u64;
typedef __attribute__((ext_vector_type(8))) short bf16x8;   // 8 bf16 in 4 VGPRs
typedef __attribute__((ext_vector_type(4))) float f32x4;

__device__ __forceinline__ float bf2f(u16 u){ union { unsigned int i; float f; } v; v.i = ((unsigned int)u)<<16; return v.f; }
__device__ __forceinline__ u16 f2bf(float f){ union { float ff; unsigned int i; } v; v.ff = f; unsigned int x = v.i; return (u16)((x + 0x7fffu + ((x>>16)&1u))>>16); }
// fast inf-safe activations: hardware rcp (1 trans) instead of precise div.
__device__ __forceinline__ float ftanh(float x){
  float e = __expf(2.f*x);
  return __builtin_fmaf(-2.f, __builtin_amdgcn_rcpf(1.f+e), 1.f);
}
__device__ __forceinline__ float sigm(float x){
  return __builtin_amdgcn_rcpf(1.f + __expf(-x));
}

// ---------------- prep kernels ----------------
__global__ void k_cast(const float* __restrict__ in, u16* __restrict__ out, long n){
  for (long i = (long)blockIdx.x*blockDim.x + threadIdx.x; i < n; i += (long)gridDim.x*blockDim.x)
    out[i] = f2bf(in[i]);
}

__global__ void k_w1cat(const float* __restrict__ wih1, const float* __restrict__ whh1, u16* __restrict__ out){
  const long n = (long)4096*2048;
  for (long i = (long)blockIdx.x*blockDim.x + threadIdx.x; i < n; i += (long)gridDim.x*blockDim.x){
    int row = (int)(i >> 11), k = (int)(i & 2047);
    float v = (k < D_) ? wih1[(size_t)row*D_ + k] : whh1[(size_t)row*D_ + (k - D_)];
    out[i] = f2bf(v);
  }
}

__global__ void k_bias(const float* __restrict__ bih, const float* __restrict__ bhh,
                       const float* __restrict__ bcv, const float* __restrict__ abias,
                       const float* __restrict__ Wcv, const float* __restrict__ fcw,
                       float* __restrict__ bias0, float* __restrict__ bias1,
                       float* __restrict__ biasE, float* __restrict__ convw){
  int i = blockIdx.x*blockDim.x + threadIdx.x;
  if (i < 4096){ bias0[i] = bih[i]+bhh[i]; bias1[i] = bih[4096+i]+bhh[4096+i]; }
  if (i < 1024){
    biasE[i] = bcv[i]+abias[i];
    convw[i*4+0]=Wcv[i*3+0]; convw[i*4+1]=Wcv[i*3+1]; convw[i*4+2]=Wcv[i*3+2]; convw[i*4+3]=fcw[i];
  }
}

__global__ void k_gather(const float* __restrict__ emb, const int* __restrict__ tgt, u16* __restrict__ embA){
  int row = blockIdx.x;            // row = t*32 + b
  int t = row >> 5, b = row & 31;
  int e = tgt[b*T_ + t];
  const float* src = emb + (size_t)e*D_;
  u16* dst = embA + (size_t)row*D_;
  for (int d = threadIdx.x; d < D_; d += 256) dst[d] = f2bf(src[d]);
}

// ---------------- big MFMA GEMM: C = A(M x K, lda) @ B(N x K)^T (+bias)(+act) ----------------
__device__ __forceinline__ void gld_lds(const u16* g, u16* l){
  __builtin_amdgcn_global_load_lds((const __attribute__((address_space(1))) unsigned int*)g,
                                   (__attribute__((address_space(3))) unsigned int*)l, 16, 0, 0);
}

template<int OUT_MODE, bool SWIZ>   // OUT_MODE: 0 f32, 1 bf16, 2 tanh->bf16 ; SWIZ: row(t*32+b)->(b*128+t)
__global__ __launch_bounds__(256) void k_gemm128(const u16* __restrict__ Am, const u16* __restrict__ Bm,
      const float* __restrict__ bias, void* __restrict__ Cout, int M, int N, int K, int lda, int ldc)
{
  __shared__ u16 As[128*32];
  __shared__ u16 Bs[128*32];
  int bm = blockIdx.y*128, bn = blockIdx.x*128;
  int tid = threadIdx.x;
  int wv = tid>>6, lane = tid&63;
  int wm = (wv>>1)*64, wn = (wv&1)*64;
  int r = lane&15, kh = lane>>4;
  f32x4 zero = {0.f,0.f,0.f,0.f};
  f32x4 acc[4][4];
  #pragma unroll
  for (int mi=0;mi<4;mi++)
    #pragma unroll
    for (int ni=0;ni<4;ni++) acc[mi][ni] = zero;

  for (int k0 = 0; k0 < K; k0 += 32){
    #pragma unroll
    for (int i=0;i<2;i++){
      int c = tid + i*256;
      int row = c>>2, ko = (c&3)*8;
      int ga = bm+row; if (ga > M-1) ga = M-1;
      gld_lds(Am + (size_t)ga*lda + k0 + ko, As + c*8);
      int gb = bn+row; if (gb > N-1) gb = N-1;
      gld_lds(Bm + (size_t)gb*K + k0 + ko, Bs + c*8);
    }
    __syncthreads();
    bf16x8 af[4], bfv[4];
    #pragma unroll
    for (int mi=0;mi<4;mi++) af[mi]  = *(const bf16x8*)(As + (wm+mi*16+r)*32 + kh*8);
    #pragma unroll
    for (int ni=0;ni<4;ni++) bfv[ni] = *(const bf16x8*)(Bs + (wn+ni*16+r)*32 + kh*8);
    #pragma unroll
    for (int mi=0;mi<4;mi++)
      #pragma unroll
      for (int ni=0;ni<4;ni++)
        acc[mi][ni] = __builtin_amdgcn_mfma_f32_16x16x32_bf16(af[mi], bfv[ni], acc[mi][ni], 0,0,0);
    __syncthreads();
  }
  #pragma unroll
  for (int mi=0;mi<4;mi++)
    #pragma unroll
    for (int ni=0;ni<4;ni++)
      #pragma unroll
      for (int rr=0;rr<4;rr++){
        int grow = bm+wm+mi*16+kh*4+rr;
        int gcol = bn+wn+ni*16+r;
        if (grow < M && gcol < N){
          float v = acc[mi][ni][rr];
          if (bias) v += bias[gcol];
          size_t orow = SWIZ ? (size_t)((grow&31)*T_ + (grow>>5)) : (size_t)grow;
          if (OUT_MODE==0)      ((float*)Cout)[orow*(size_t)ldc + gcol] = v;
          else if (OUT_MODE==1) ((u16*)Cout)[orow*(size_t)ldc + gcol] = f2bf(v);
          else                  ((u16*)Cout)[orow*(size_t)ldc + gcol] = f2bf(ftanh(v));
        }
      }
}

// ---------------- hierarchical fence-free barrier (256 blocks) ----------------
__device__ __forceinline__ void xcd_barrier(int* barL, int it){
  asm volatile("s_waitcnt vmcnt(0)" ::: "memory");
  __syncthreads();
  if (threadIdx.x==0){
    int grp = blockIdx.x & 7;
    int* gcnt = barL + grp*32;
    int* root = barL + 256;
    int* rel  = barL + 320 + grp*32;
    int v = __hip_atomic_fetch_add(gcnt, 1, __ATOMIC_RELAXED, __HIP_MEMORY_SCOPE_AGENT);
    if (v == 32*(it+1) - 1){                    // last of my group this iteration
      int rv = __hip_atomic_fetch_add(root, 1, __ATOMIC_RELAXED, __HIP_MEMORY_SCOPE_AGENT);
      if (rv == 8*(it+1) - 1){                  // last group overall -> release all
        #pragma unroll
        for (int g2=0; g2<8; ++g2)
          __hip_atomic_store(barL + 320 + g2*32, it+1, __ATOMIC_RELAXED, __HIP_MEMORY_SCOPE_AGENT);
      }
    }
    while (__hip_atomic_load(rel, __ATOMIC_RELAXED, __HIP_MEMORY_SCOPE_AGENT) < it+1)
      __builtin_amdgcn_s_sleep(8);
  }
  __syncthreads();
}

// ---------------- small-group barrier (attention: 8 blocks/batch, own cache line) ----------------
__device__ __forceinline__ void ring_barrier(int* cnt, int nblk, int it){
  asm volatile("s_waitcnt vmcnt(0)" ::: "memory");
  __syncthreads();
  if (threadIdx.x==0){
    __hip_atomic_fetch_add(cnt, 1, __ATOMIC_RELAXED, __HIP_MEMORY_SCOPE_AGENT);
    int target = nblk*(it+1);
    while (__hip_atomic_load(cnt, __ATOMIC_RELAXED, __HIP_MEMORY_SCOPE_AGENT) < target)
      __builtin_amdgcn_s_sleep(4);
  }
  __syncthreads();
}

// ---------------- persistent LSTM (+ folded qp): weights resident in LDS, 1 barrier/step ----------------
// Pipeline at iter p: G0(p) | G1(p-1) | qp(p-2) (waves 4-7's a_g1 h1-half regs vs Wq LDS slice).
// qps is consumed only by k_attn_p AFTER this kernel -> plain stores (kernel-boundary coherence).
__global__ __launch_bounds__(512) void k_lstm_p(const u16* __restrict__ Whh0, const u16* __restrict__ W1cat,
    const u16* __restrict__ Wqm, const u16* __restrict__ X0, const float* __restrict__ bias1,
    u16* __restrict__ Hh, u16* __restrict__ qcat, u16* __restrict__ qps, int* __restrict__ barL)
{
  __shared__ u16 W0s[16*1024];     // 32 KB  (16 out-rows x K=1024, 16B-chunk XOR swizzle)
  __shared__ u16 W1s[16*2048];     // 64 KB  (16 out-rows x K=2048)
  __shared__ u16 Wqs[4*1024];      // 8 KB   (qp weight slice, 4 cols)
  __shared__ float gl0[8*512];     // 16 KB  8-wave partials, layer0
  __shared__ float gl1[8*512];     // 16 KB  layer1
  __shared__ float glq[4*128];     // 2 KB   (waves 4-7 qp partials)
  __shared__ u16 hb0[128];
  __shared__ u16 hb1[128];
  int bid = blockIdx.x, tid = threadIdx.x;
  int w = tid>>6, lane = tid&63, r = lane&15, kh = lane>>4;
  // ---- stage this block's weight slices into LDS once ----
  for (int ci = tid; ci < 2048; ci += 512){
    int row = ci>>7, c = ci&127;
    int grow = (row>>2)*1024 + bid*4 + (row&3);          // gate-major row in Whh0
    bf16x8 v = *(const bf16x8*)(Whh0 + (size_t)grow*1024 + c*8);
    *(bf16x8*)(W0s + (size_t)(((row<<7) + (c ^ (row&7)))*8)) = v;
  }
  for (int ci = tid; ci < 4096; ci += 512){
    int row = ci>>8, c = ci&255;
    int grow = (row>>2)*1024 + bid*4 + (row&3);
    bf16x8 v = *(const bf16x8*)(W1cat + (size_t)grow*2048 + c*8);
    *(bf16x8*)(W1s + (size_t)(((row<<8) + (c ^ (row&7)))*8)) = v;
  }
  {
    int row = tid>>7, c = tid&127;   // 512 = 4 rows x 128 chunks
    bf16x8 v = *(const bf16x8*)(Wqm + (size_t)(bid*4+row)*1024 + c*8);
    *(bf16x8*)(Wqs + (size_t)(((row<<7) + (c ^ (row&7)))*8)) = v;
  }
  __syncthreads();
  float c0reg = 0.f, c1reg = 0.f;
  int cb = tid>>2, cj = tid&3;            // (tid<128): cell (batch cb, local col cj)
  int col = bid*4 + cj;
  float b1i=0.f, b1f=0.f, b1g=0.f, b1o=0.f;
  if (tid < 128){ b1i=bias1[col]; b1f=bias1[1024+col]; b1g=bias1[2048+col]; b1o=bias1[3072+col]; }
  for (int p = 0; p <= T_+1; ++p){
    const u16* Hprev = Hh + (size_t)p*65536;       // slot p-1
    u16* Hcur = (u16*)Hh + (size_t)(p+1)*65536;    // slot p
    bool doG0 = (p < T_);
    bool doG1 = (p >= 1 && p <= T_);
    bool loadG1 = (p >= 1);
    bool doQP = (p >= 2);
    // ---- prefetch X0 gate terms early (hides scattered LLC reads under MFMA) ----
    float x_gi=0.f, x_gf=0.f, x_gg=0.f, x_go=0.f;
    if (doG0 && tid < 128){
      const u16* xr = X0 + ((size_t)p*32 + cb)*4096 + col;
      x_gi = bf2f(xr[0]); x_gf = bf2f(xr[1024]); x_gg = bf2f(xr[2048]); x_go = bf2f(xr[3072]);
    }
    f32x4 acc00={0.f,0.f,0.f,0.f}, acc01={0.f,0.f,0.f,0.f};
    f32x4 acc10={0.f,0.f,0.f,0.f}, acc11={0.f,0.f,0.f,0.f};
    f32x4 accq0={0.f,0.f,0.f,0.f}, accq1={0.f,0.f,0.f,0.f};
    bf16x8 a_g0[2][4], a_g1[2][8];
    // ---- issue ALL A-loads up front (normal cached loads, L2-served broadcast) ----
    if (doG0){
      const u16* a0 = Hprev + (size_t)r*2048 + w*128 + kh*8;
      const u16* a1 = Hprev + (size_t)(16+r)*2048 + w*128 + kh*8;
      #pragma unroll
      for (int kk=0;kk<4;kk++){ a_g0[0][kk] = *(const bf16x8*)(a0 + kk*32);
                                a_g0[1][kk] = *(const bf16x8*)(a1 + kk*32); }
    }
    if (loadG1){
      const u16* a0 = Hprev + (size_t)r*2048 + w*256 + kh*8;
      const u16* a1 = Hprev + (size_t)(16+r)*2048 + w*256 + kh*8;
      #pragma unroll
      for (int kk=0;kk<8;kk++){ a_g1[0][kk] = *(const bf16x8*)(a0 + kk*32);
                                a_g1[1][kk] = *(const bf16x8*)(a1 + kk*32); }
    }
    // ---- MFMA from LDS weights ----
    if (doG0){
      #pragma unroll
      for (int kk=0;kk<4;kk++){
        int c = (w<<4) + (kk<<2) + kh;
        bf16x8 bv = *(const bf16x8*)(W0s + (size_t)((((int)r<<7) + (c ^ (r&7)))*8));
        acc00 = __builtin_amdgcn_mfma_f32_16x16x32_bf16(a_g0[0][kk], bv, acc00, 0,0,0);
        acc01 = __builtin_amdgcn_mfma_f32_16x16x32_bf16(a_g0[1][kk], bv, acc01, 0,0,0);
      }
    }
    if (doG1){
      #pragma unroll
      for (int kk=0;kk<8;kk++){
        int c = (w<<5) + (kk<<2) + kh;
        bf16x8 bv = *(const bf16x8*)(W1s + (size_t)((((int)r<<8) + (c ^ (r&7)))*8));
        acc10 = __builtin_amdgcn_mfma_f32_16x16x32_bf16(a_g1[0][kk], bv, acc10, 0,0,0);
        acc11 = __builtin_amdgcn_mfma_f32_16x16x32_bf16(a_g1[1][kk], bv, acc11, 0,0,0);
      }
    }
    if (doQP && w >= 4){   // qp(p-2) = h1(p-2) @ Wq^T: waves 4-7's a_g1 span K=[1024,2048) = h1
      #pragma unroll
      for (int kk=0;kk<8;kk++){
        int c = ((w-4)<<5) + (kk<<2) + kh;
        int qrw = r & 3;   // only 4 real B rows; cols 4-15 are discarded duplicates
        bf16x8 bv = *(const bf16x8*)(Wqs + (size_t)(((qrw<<7) + (c ^ (qrw&7)))*8));
        accq0 = __builtin_amdgcn_mfma_f32_16x16x32_bf16(a_g1[0][kk], bv, accq0, 0,0,0);
        accq1 = __builtin_amdgcn_mfma_f32_16x16x32_bf16(a_g1[1][kk], bv, accq1, 0,0,0);
      }
    }
    // ---- one-sync cross-wave reduce + cells ----
    #pragma unroll
    for (int rr=0;rr<4;rr++){
      gl0[w*512 + (kh*4+rr)*16 + r]    = acc00[rr];
      gl0[w*512 + (16+kh*4+rr)*16 + r] = acc01[rr];
      gl1[w*512 + (kh*4+rr)*16 + r]    = acc10[rr];
      gl1[w*512 + (16+kh*4+rr)*16 + r] = acc11[rr];
    }
    if (doQP && w >= 4 && r < 4){
      #pragma unroll
      for (int rr=0;rr<4;rr++){
        glq[(w-4)*128 + (kh*4+rr)*4 + r]    = accq0[rr];
        glq[(w-4)*128 + (16+kh*4+rr)*4 + r] = accq1[rr];
      }
    }
    __syncthreads();
    if (tid < 128){
      if (doG0){
        float gi=x_gi, gf=x_gf, gg=x_gg, go=x_go;
        #pragma unroll
        for (int ww=0;ww<8;ww++){
          const float* gp = gl0 + ww*512 + cb*16 + cj;
          gi += gp[0]; gf += gp[4]; gg += gp[8]; go += gp[12];
        }
        float cn = sigm(gf)*c0reg + sigm(gi)*ftanh(gg);
        float hn = sigm(go)*ftanh(cn); c0reg = cn;
        hb0[tid] = f2bf(hn);
      }
      if (doG1){
        float gi=b1i, gf=b1f, gg=b1g, go=b1o;
        #pragma unroll
        for (int ww=0;ww<8;ww++){
          const float* gp = gl1 + ww*512 + cb*16 + cj;
          gi += gp[0]; gf += gp[4]; gg += gp[8]; go += gp[12];
        }
        float cn = sigm(gf)*c1reg + sigm(gi)*ftanh(gg);
        float hn = sigm(go)*ftanh(cn); c1reg = cn;
        hb1[tid] = f2bf(hn);
      }
      if (doQP){
        float hq = glq[cb*4+cj] + glq[128 + cb*4+cj] + glq[256 + cb*4+cj] + glq[384 + cb*4+cj];
        qps[((size_t)(p-2)*32 + cb)*1024 + col] = f2bf(hq);   // plain store; read post-kernel
      }
    }
    __syncthreads();
    // ---- packed coherent h stores + q output (tid<32, one u64 each) ----
    if (tid < 32){
      union { u64 v; u16 s[4]; } pk;
      if (doG0){
        pk.s[0]=hb0[tid*4]; pk.s[1]=hb0[tid*4+1]; pk.s[2]=hb0[tid*4+2]; pk.s[3]=hb0[tid*4+3];
        __hip_atomic_store((u64*)(Hcur + (size_t)tid*2048 + bid*4), pk.v,
                           __ATOMIC_RELAXED, __HIP_MEMORY_SCOPE_AGENT);
      }
      if (doG1){
        pk.s[0]=hb1[tid*4]; pk.s[1]=hb1[tid*4+1]; pk.s[2]=hb1[tid*4+2]; pk.s[3]=hb1[tid*4+3];
        __hip_atomic_store((u64*)(Hcur + (size_t)tid*2048 + 1024 + bid*4), pk.v,
                           __ATOMIC_RELAXED, __HIP_MEMORY_SCOPE_AGENT);
        *(u64*)(qcat + ((size_t)(p-1)*32 + tid)*2048 + bid*4) = pk.v;   // q, normal store
      }
    }
    if (p < T_+1) xcd_barrier(barL, p);
  }
}

// ---------------- persistent attention: 8 blocks/batch x 512 thr ----------------
__global__ __launch_bounds__(512) void k_attn_p(const u16* __restrict__ vpb, const u16* __restrict__ qpb,
    const u16* __restrict__ enc, const float* __restrict__ convw,
    float* __restrict__ eng, u16* __restrict__ qcat, int* __restrict__ barA)
{
  __shared__ float aw[256];
  __shared__ float red[16];
  __shared__ float cred[512];
  int bid = blockIdx.x, tid = threadIdx.x;
  int b = bid>>3, p = bid&7;
  int w = tid>>6, lane = tid&63;
  int d0 = lane*16;
  f32x4 cw[16];
  #pragma unroll
  for (int j=0;j<16;j++) cw[j] = *(const f32x4*)(convw + (size_t)(d0+j)*4);
  if (tid < 256) aw[tid] = 0.f;
  __syncthreads();
  int* cnt = barA + b*32;
  for (int t=0; t<T_; ++t){
    float* ebuf = eng + (t&1)*8192 + b*256;
    // ---- energy: this block covers s in [p*32, p*32+32); wave w does 4 s ----
    const u16* qrow = qpb + ((size_t)t*32 + b)*1024 + d0;
    bf16x8 q0 = *(const bf16x8*)qrow, q1 = *(const bf16x8*)(qrow+8);
    float qf[16];
    #pragma unroll
    for (int j=0;j<16;j++) qf[j] = bf2f((u16)(j<8 ? q0[j] : q1[j-8]));
    #pragma unroll
    for (int ss=0; ss<4; ++ss){
      int s = p*32 + w*4 + ss;
      float am = (s>0)   ? aw[s-1] : 0.f;
      float ac =           aw[s];
      float ap = (s<255) ? aw[s+1] : 0.f;
      const u16* vrow = vpb + ((size_t)(b*256+s))*1024 + d0;
      bf16x8 v0 = *(const bf16x8*)vrow, v1 = *(const bf16x8*)(vrow+8);
      float sum = 0.f;
      #pragma unroll
      for (int j=0;j<16;j++){
        float vv = bf2f((u16)(j<8 ? v0[j] : v1[j-8]));
        float x = qf[j] + vv + am*cw[j][0] + ac*cw[j][1] + ap*cw[j][2];
        sum += ftanh(x)*cw[j][3];
      }
      #pragma unroll
      for (int o=32;o;o>>=1) sum += __shfl_xor(sum, o);
      if (lane==0)
        __hip_atomic_store(ebuf + s, sum, __ATOMIC_RELAXED, __HIP_MEMORY_SCOPE_AGENT);
    }
    ring_barrier(cnt, 8, t);
    // ---- softmax over 256 (redundant per block, coherent energy loads) ----
    float e_val = -3.0e38f;
    if (tid < 256)
      e_val = __hip_atomic_load(ebuf + tid, __ATOMIC_RELAXED, __HIP_MEMORY_SCOPE_AGENT);
    float m = e_val;
    #pragma unroll
    for (int o=32;o;o>>=1) m = fmaxf(m, __shfl_xor(m,o));
    if (lane==0) red[w] = m;
    __syncthreads();
    float mx = red[0];
    #pragma unroll
    for (int i2=1;i2<8;i2++) mx = fmaxf(mx, red[i2]);
    float ex = (tid < 256) ? __expf(e_val - mx) : 0.f;
    float sl = ex;
    #pragma unroll
    for (int o=32;o;o>>=1) sl += __shfl_xor(sl,o);
    __syncthreads();
    if (lane==0) red[8+w] = sl;
    __syncthreads();
    float st = red[8]+red[9]+red[10]+red[11]+red[12]+red[13]+red[14]+red[15];
    if (tid < 256) aw[tid] = ex * __builtin_amdgcn_rcpf(st);
    __syncthreads();
    // ---- context slice d in [p*128, p*128+128): 4-way s-split ----
    int sq = tid>>7, dt = tid&127;
    const u16* ep = enc + (size_t)(b*256 + sq*64)*1024 + p*128 + dt;
    float a0=0.f,a1=0.f,a2=0.f,a3=0.f;
    #pragma unroll 4
    for (int s2=0;s2<64;s2+=4){
      a0 += aw[sq*64+s2]   * bf2f(ep[(size_t)(s2)  *1024]);
      a1 += aw[sq*64+s2+1] * bf2f(ep[(size_t)(s2+1)*1024]);
      a2 += aw[sq*64+s2+2] * bf2f(ep[(size_t)(s2+2)*1024]);
      a3 += aw[sq*64+s2+3] * bf2f(ep[(size_t)(s2+3)*1024]);
    }
    cred[tid] = a0+a1+a2+a3;
    __syncthreads();
    if (tid < 128)
      qcat[((size_t)t*32 + b)*2048 + 1024 + p*128 + tid] =
        f2bf(cred[tid]+cred[128+tid]+cred[256+tid]+cred[384+tid]);
    __syncthreads();
  }
}

// in-place log_softmax over V per row of out (register-cached, 2 passes of traffic)
__global__ __launch_bounds__(256) void k_logsm(float* __restrict__ out){
  int row = blockIdx.x, tid = threadIdx.x;
  float* p = out + (size_t)row*V_;
  __shared__ float red[4];
  float pv[40];
  int nv = 0;
  float mx = -3.0e38f;
  for (int v=tid; v<V_; v+=256){ float x = p[v]; pv[nv++] = x; mx = fmaxf(mx, x); }
  #pragma unroll
  for (int o=32;o;o>>=1) mx = fmaxf(mx, __shfl_xor(mx,o));
  if ((tid&63)==0) red[tid>>6]=mx;
  __syncthreads();
  mx = fmaxf(fmaxf(red[0],red[1]),fmaxf(red[2],red[3]));
  __syncthreads();
  float s = 0.f;
  for (int i=0;i<nv;i++) s += __expf(pv[i]-mx);
  #pragma unroll
  for (int o=32;o;o>>=1) s += __shfl_xor(s,o);
  if ((tid&63)==0) red[tid>>6]=s;
  __syncthreads();
  float lz = mx + __logf(red[0]+red[1]+red[2]+red[3]);
  { int i=0; for (int v=tid; v<V_; v+=256) p[v] = pv[i++] - lz; }
}

// ---------------- host ----------------
extern "C" void kernel_launch(void* const* d_in, const int* in_sizes, int n_in,
                              void* d_out, int out_size, void* d_ws, size_t ws_size,
                              hipStream_t stream)
{
  const float* enc   = (const float*)d_in[0];
  const int*   tgt   = (const int*)  d_in[1];
  const float* emb   = (const float*)d_in[2];
  const float* Wih   = (const float*)d_in[3];
  const float* Whh   = (const float*)d_in[4];
  const float* bih   = (const float*)d_in[5];
  const float* bhh   = (const float*)d_in[6];
  const float* Wcv   = (const float*)d_in[7];
  const float* bcv   = (const float*)d_in[8];
  const float* Wq    = (const float*)d_in[9];
  const float* Wvm   = (const float*)d_in[10];
  const float* abias = (const float*)d_in[11];
  const float* fcw   = (const float*)d_in[12];
  // d_in[13] fc_attn_b: softmax-invariant, unused
  const float* fc1w  = (const float*)d_in[14];
  const float* fc1b  = (const float*)d_in[15];
  const float* fc2w  = (const float*)d_in[16];
  const float* fc2b  = (const float*)d_in[17];
  float* out = (float*)d_out;

  char* base = (char*)d_ws; size_t off = 0;
  auto A = [&](size_t nbytes)->char*{ char* q = base + off; off += (nbytes + 255) & ~(size_t)255; return q; };
  u16* enc_bf  = (u16*)A(8388608ull*2);
  u16* Wv_bf   = (u16*)A(1048576ull*2);
  u16* Wih0_bf = (u16*)A(4194304ull*2);
  u16* W1cat   = (u16*)A(8388608ull*2);
  u16* Whh0_bf = (u16*)A(4194304ull*2);
  u16* Wq_bf   = (u16*)A(1048576ull*2);
  u16* fc1w_bf = (u16*)A(2097152ull*2);
  u16* fc2w_bf = (u16*)A(10240000ull*2);  // ALSO aliased as Hh during the LSTM phase
  u16* embA    = (u16*)A(4194304ull*2);   // reused: X0-GEMM A -> qps -> hid
  u16* X0      = (u16*)A(16777216ull*2);  // (T*32, 4096) bf16, includes bias0
  u16* vpb     = (u16*)A(8388608ull*2);   // bf16(vproj + bconv + attn_bias)
  u16* qcat    = (u16*)A(8388608ull*2);   // (T*32, 2048) = [q | context]
  float* bias0 = (float*)A(4096*4);
  float* bias1 = (float*)A(4096*4);
  float* biasE = (float*)A(1024*4);
  float* convw = (float*)A(4096*4);       // [d][{Wc0,Wc1,Wc2,fcw}]
  float* eng   = (float*)A(2*8192*4);     // attn energy double buffer
  int* barL    = (int*)A(4096);           // hierarchical barrier, 128B-padded lines
  int* barA    = (int*)A(4096);           // 32 batches x 32-int (128B) lines
  u16* Hh      = fc2w_bf;                 // 131 slots x (32x2048) bf16 = 17.2 MB <= 20.48 MB
  u16* qps     = embA;                    // (T*32, 1024) bf16 qp (embA free after X0 GEMM)
  u16* hid     = embA;

  // zero h-history slots -1 and 0 + barriers (re-done on every graph replay)
  hipMemsetAsync(Hh, 0, 2*65536*2, stream);
  hipMemsetAsync(barL, 0, 4096, stream);
  hipMemsetAsync(barA, 0, 4096, stream);

  // prep: bf16 casts (fc2w cast DEFERRED until after LSTM+attn; its buffer holds Hh now)
  k_cast<<<2048,256,0,stream>>>(enc,  enc_bf,  8388608);
  k_cast<<<1024,256,0,stream>>>(Wih,  Wih0_bf, 4194304);
  k_cast<<<1024,256,0,stream>>>(Whh,  Whh0_bf, 4194304);
  k_cast<<<512,256,0,stream>>>(Wq,    Wq_bf,   1048576);
  k_cast<<<512,256,0,stream>>>(Wvm,   Wv_bf,   1048576);
  k_cast<<<512,256,0,stream>>>(fc1w,  fc1w_bf, 2097152);
  k_w1cat<<<2048,256,0,stream>>>(Wih + 4194304, Whh + 4194304, W1cat);
  k_bias<<<16,256,0,stream>>>(bih, bhh, bcv, abias, Wcv, fcw, bias0, bias1, biasE, convw);
  k_gather<<<4096,256,0,stream>>>(emb, tgt, embA);

  // vpb = bf16(enc @ Wv^T + (bconv + attn_bias))   (8192 x 1024 x 1024)
  k_gemm128<1,false><<<dim3(8,64),256,0,stream>>>(enc_bf, Wv_bf, biasE, vpb, 8192, 1024, 1024, 1024, 1024);
  // X0 = bf16(emb[targets] @ W_ih0^T + (b_ih0+b_hh0))  (4096 x 4096 x 1024)
  k_gemm128<1,false><<<dim3(32,32),256,0,stream>>>(embA, Wih0_bf, bias0, X0, 4096, 4096, 1024, 1024, 4096);

  // ---- persistent LSTM loop (256 blocks, weights in LDS, folded qp, hierarchical barrier) ----
  {
    const u16* a0 = Whh0_bf; const u16* a1 = W1cat; const u16* a2 = Wq_bf; const u16* a3 = X0;
    const float* a4 = bias1; u16* a5 = Hh; u16* a6 = qcat; u16* a7 = qps; int* a8 = barL;
    void* args[] = {(void*)&a0,(void*)&a1,(void*)&a2,(void*)&a3,(void*)&a4,(void*)&a5,
                    (void*)&a6,(void*)&a7,(void*)&a8};
    hipError_t e = hipLaunchCooperativeKernel((const void*)k_lstm_p, dim3(256), dim3(512), args, 0, stream);
    if (e != hipSuccess)
      k_lstm_p<<<dim3(256),dim3(512),0,stream>>>(a0,a1,a2,a3,a4,a5,a6,a7,a8);
  }

  // ---- persistent attention loop (256 blocks x 512 thr, per-batch barrier) ----
  {
    const u16* a0 = vpb; const u16* a1 = qps; const u16* a2 = enc_bf; const float* a3 = convw;
    float* a4 = eng; u16* a5 = qcat; int* a6 = barA;
    void* args[] = {(void*)&a0,(void*)&a1,(void*)&a2,(void*)&a3,(void*)&a4,(void*)&a5,(void*)&a6};
    hipError_t e = hipLaunchCooperativeKernel((const void*)k_attn_p, dim3(256), dim3(512), args, 0, stream);
    if (e != hipSuccess)
      k_attn_p<<<dim3(256),dim3(512),0,stream>>>(a0,a1,a2,a3,a4,a5,a6);
  }

  // hid = tanh(qcat @ fc1w^T + fc1b)   (4096 x 1024 x 2048)
  k_gemm128<2,false><<<dim3(8,32),256,0,stream>>>(qcat, fc1w_bf, fc1b, hid, 4096, 1024, 2048, 2048, 1024);
  // fc2 weight cast (deferred; Hh no longer needed)
  k_cast<<<2048,256,0,stream>>>(fc2w, fc2w_bf, 10240000);
  // logits = hid @ fc2w^T + fc2b -> out[b][t][v]  (4096 x 10000 x 1024, row swizzle (t,b)->(b,t))
  k_gemm128<0,true><<<dim3(79,32),256,0,stream>>>(hid, fc2w_bf, fc2b, out, 4096, V_, 1024, 1024, V_);
  // in-place log_softmax over V
  k_logsm<<<4096,256,0,stream>>>(out);
}

// Round 15
// 2785.892 us; speedup vs baseline: 3.5618x; 1.0082x over previous
//
#include <hip/hip_runtime.h>
#include <stdint.h>

#define B_ 32
#define T_ 128
#define S_ 256
#define D_ 1024
#define V_ 10000

typedef unsigned short u16;
typedef unsigned long long u64;
typedef __attribute__((ext_vector_type(8))) short bf16x8;   // 8 bf16 in 4 VGPRs
typedef __attribute__((ext_vector_type(4))) float f32x4;

__device__ __forceinline__ float bf2f(u16 u){ union { unsigned int i; float f; } v; v.i = ((unsigned int)u)<<16; return v.f; }
__device__ __forceinline__ u16 f2bf(float f){ union { float ff; unsigned int i; } v; v.ff = f; unsigned int x = v.i; return (u16)((x + 0x7fffu + ((x>>16)&1u))>>16); }
// fast inf-safe activations: hardware rcp (1 trans) instead of precise div.
__device__ __forceinline__ float ftanh(float x){
  float e = __expf(2.f*x);
  return __builtin_fmaf(-2.f, __builtin_amdgcn_rcpf(1.f+e), 1.f);
}
__device__ __forceinline__ float sigm(float x){
  return __builtin_amdgcn_rcpf(1.f + __expf(-x));
}

// ---------------- prep kernels ----------------
__global__ void k_cast(const float* __restrict__ in, u16* __restrict__ out, long n){
  for (long i = (long)blockIdx.x*blockDim.x + threadIdx.x; i < n; i += (long)gridDim.x*blockDim.x)
    out[i] = f2bf(in[i]);
}

__global__ void k_w1cat(const float* __restrict__ wih1, const float* __restrict__ whh1, u16* __restrict__ out){
  const long n = (long)4096*2048;
  for (long i = (long)blockIdx.x*blockDim.x + threadIdx.x; i < n; i += (long)gridDim.x*blockDim.x){
    int row = (int)(i >> 11), k = (int)(i & 2047);
    float v = (k < D_) ? wih1[(size_t)row*D_ + k] : whh1[(size_t)row*D_ + (k - D_)];
    out[i] = f2bf(v);
  }
}

__global__ void k_bias(const float* __restrict__ bih, const float* __restrict__ bhh,
                       const float* __restrict__ bcv, const float* __restrict__ abias,
                       const float* __restrict__ Wcv, const float* __restrict__ fcw,
                       float* __restrict__ bias0, float* __restrict__ bias1,
                       float* __restrict__ biasE, float* __restrict__ convw){
  int i = blockIdx.x*blockDim.x + threadIdx.x;
  if (i < 4096){ bias0[i] = bih[i]+bhh[i]; bias1[i] = bih[4096+i]+bhh[4096+i]; }
  if (i < 1024){
    biasE[i] = bcv[i]+abias[i];
    convw[i*4+0]=Wcv[i*3+0]; convw[i*4+1]=Wcv[i*3+1]; convw[i*4+2]=Wcv[i*3+2]; convw[i*4+3]=fcw[i];
  }
}

__global__ void k_gather(const float* __restrict__ emb, const int* __restrict__ tgt, u16* __restrict__ embA){
  int row = blockIdx.x;            // row = t*32 + b
  int t = row >> 5, b = row & 31;
  int e = tgt[b*T_ + t];
  const float* src = emb + (size_t)e*D_;
  u16* dst = embA + (size_t)row*D_;
  for (int d = threadIdx.x; d < D_; d += 256) dst[d] = f2bf(src[d]);
}

// ---------------- big MFMA GEMM: C = A(M x K, lda) @ B(N x K)^T (+bias)(+act) ----------------
__device__ __forceinline__ void gld_lds(const u16* g, u16* l){
  __builtin_amdgcn_global_load_lds((const __attribute__((address_space(1))) unsigned int*)g,
                                   (__attribute__((address_space(3))) unsigned int*)l, 16, 0, 0);
}

template<int OUT_MODE, bool SWIZ>   // OUT_MODE: 0 f32, 1 bf16, 2 tanh->bf16 ; SWIZ: row(t*32+b)->(b*128+t)
__global__ __launch_bounds__(256) void k_gemm128(const u16* __restrict__ Am, const u16* __restrict__ Bm,
      const float* __restrict__ bias, void* __restrict__ Cout, int M, int N, int K, int lda, int ldc)
{
  __shared__ u16 As[128*32];
  __shared__ u16 Bs[128*32];
  int bm = blockIdx.y*128, bn = blockIdx.x*128;
  int tid = threadIdx.x;
  int wv = tid>>6, lane = tid&63;
  int wm = (wv>>1)*64, wn = (wv&1)*64;
  int r = lane&15, kh = lane>>4;
  f32x4 zero = {0.f,0.f,0.f,0.f};
  f32x4 acc[4][4];
  #pragma unroll
  for (int mi=0;mi<4;mi++)
    #pragma unroll
    for (int ni=0;ni<4;ni++) acc[mi][ni] = zero;

  for (int k0 = 0; k0 < K; k0 += 32){
    #pragma unroll
    for (int i=0;i<2;i++){
      int c = tid + i*256;
      int row = c>>2, ko = (c&3)*8;
      int ga = bm+row; if (ga > M-1) ga = M-1;
      gld_lds(Am + (size_t)ga*lda + k0 + ko, As + c*8);
      int gb = bn+row; if (gb > N-1) gb = N-1;
      gld_lds(Bm + (size_t)gb*K + k0 + ko, Bs + c*8);
    }
    __syncthreads();
    bf16x8 af[4], bfv[4];
    #pragma unroll
    for (int mi=0;mi<4;mi++) af[mi]  = *(const bf16x8*)(As + (wm+mi*16+r)*32 + kh*8);
    #pragma unroll
    for (int ni=0;ni<4;ni++) bfv[ni] = *(const bf16x8*)(Bs + (wn+ni*16+r)*32 + kh*8);
    #pragma unroll
    for (int mi=0;mi<4;mi++)
      #pragma unroll
      for (int ni=0;ni<4;ni++)
        acc[mi][ni] = __builtin_amdgcn_mfma_f32_16x16x32_bf16(af[mi], bfv[ni], acc[mi][ni], 0,0,0);
    __syncthreads();
  }
  #pragma unroll
  for (int mi=0;mi<4;mi++)
    #pragma unroll
    for (int ni=0;ni<4;ni++)
      #pragma unroll
      for (int rr=0;rr<4;rr++){
        int grow = bm+wm+mi*16+kh*4+rr;
        int gcol = bn+wn+ni*16+r;
        if (grow < M && gcol < N){
          float v = acc[mi][ni][rr];
          if (bias) v += bias[gcol];
          size_t orow = SWIZ ? (size_t)((grow&31)*T_ + (grow>>5)) : (size_t)grow;
          if (OUT_MODE==0)      ((float*)Cout)[orow*(size_t)ldc + gcol] = v;
          else if (OUT_MODE==1) ((u16*)Cout)[orow*(size_t)ldc + gcol] = f2bf(v);
          else                  ((u16*)Cout)[orow*(size_t)ldc + gcol] = f2bf(ftanh(v));
        }
      }
}

// ---------------- hierarchical fence-free barrier (256 blocks) ----------------
__device__ __forceinline__ void xcd_barrier(int* barL, int it){
  asm volatile("s_waitcnt vmcnt(0)" ::: "memory");
  __syncthreads();
  if (threadIdx.x==0){
    int grp = blockIdx.x & 7;
    int* gcnt = barL + grp*32;
    int* root = barL + 256;
    int* rel  = barL + 320 + grp*32;
    int v = __hip_atomic_fetch_add(gcnt, 1, __ATOMIC_RELAXED, __HIP_MEMORY_SCOPE_AGENT);
    if (v == 32*(it+1) - 1){                    // last of my group this iteration
      int rv = __hip_atomic_fetch_add(root, 1, __ATOMIC_RELAXED, __HIP_MEMORY_SCOPE_AGENT);
      if (rv == 8*(it+1) - 1){                  // last group overall -> release all
        #pragma unroll
        for (int g2=0; g2<8; ++g2)
          __hip_atomic_store(barL + 320 + g2*32, it+1, __ATOMIC_RELAXED, __HIP_MEMORY_SCOPE_AGENT);
      }
    }
    while (__hip_atomic_load(rel, __ATOMIC_RELAXED, __HIP_MEMORY_SCOPE_AGENT) < it+1)
      __builtin_amdgcn_s_sleep(4);
  }
  __syncthreads();
}

// ---------------- small-group barrier (attention: 8 blocks/batch, own cache line) ----------------
__device__ __forceinline__ void ring_barrier(int* cnt, int nblk, int it){
  asm volatile("s_waitcnt vmcnt(0)" ::: "memory");
  __syncthreads();
  if (threadIdx.x==0){
    __hip_atomic_fetch_add(cnt, 1, __ATOMIC_RELAXED, __HIP_MEMORY_SCOPE_AGENT);
    int target = nblk*(it+1);
    while (__hip_atomic_load(cnt, __ATOMIC_RELAXED, __HIP_MEMORY_SCOPE_AGENT) < target)
      __builtin_amdgcn_s_sleep(4);
  }
  __syncthreads();
}

// ---------------- persistent LSTM (+ folded qp): weights resident in LDS, 1 barrier/step ----------------
// gl layout stride 17 (was 16): cell-phase ds_read banks spread ~16-way -> ~2-way conflicts (was 8-way).
__global__ __launch_bounds__(512) void k_lstm_p(const u16* __restrict__ Whh0, const u16* __restrict__ W1cat,
    const u16* __restrict__ Wqm, const u16* __restrict__ X0, const float* __restrict__ bias1,
    u16* __restrict__ Hh, u16* __restrict__ qcat, u16* __restrict__ qps, int* __restrict__ barL)
{
  __shared__ u16 W0s[16*1024];     // 32 KB
  __shared__ u16 W1s[16*2048];     // 64 KB
  __shared__ u16 Wqs[4*1024];      // 8 KB
  __shared__ float gl0[8*544];     // 17 KB  (stride 17: 32 b x 17)
  __shared__ float gl1[8*544];     // 17 KB
  __shared__ float glq[4*128];     // 2 KB
  __shared__ u16 hb0[128];
  __shared__ u16 hb1[128];
  int bid = blockIdx.x, tid = threadIdx.x;
  int w = tid>>6, lane = tid&63, r = lane&15, kh = lane>>4;
  // ---- stage this block's weight slices into LDS once ----
  for (int ci = tid; ci < 2048; ci += 512){
    int row = ci>>7, c = ci&127;
    int grow = (row>>2)*1024 + bid*4 + (row&3);          // gate-major row in Whh0
    bf16x8 v = *(const bf16x8*)(Whh0 + (size_t)grow*1024 + c*8);
    *(bf16x8*)(W0s + (size_t)(((row<<7) + (c ^ (row&7)))*8)) = v;
  }
  for (int ci = tid; ci < 4096; ci += 512){
    int row = ci>>8, c = ci&255;
    int grow = (row>>2)*1024 + bid*4 + (row&3);
    bf16x8 v = *(const bf16x8*)(W1cat + (size_t)grow*2048 + c*8);
    *(bf16x8*)(W1s + (size_t)(((row<<8) + (c ^ (row&7)))*8)) = v;
  }
  {
    int row = tid>>7, c = tid&127;   // 512 = 4 rows x 128 chunks
    bf16x8 v = *(const bf16x8*)(Wqm + (size_t)(bid*4+row)*1024 + c*8);
    *(bf16x8*)(Wqs + (size_t)(((row<<7) + (c ^ (row&7)))*8)) = v;
  }
  __syncthreads();
  float c0reg = 0.f, c1reg = 0.f;
  int cb = tid>>2, cj = tid&3;            // (tid<128): cell (batch cb, local col cj)
  int col = bid*4 + cj;
  float b1i=0.f, b1f=0.f, b1g=0.f, b1o=0.f;
  if (tid < 128){ b1i=bias1[col]; b1f=bias1[1024+col]; b1g=bias1[2048+col]; b1o=bias1[3072+col]; }
  for (int p = 0; p <= T_+1; ++p){
    const u16* Hprev = Hh + (size_t)p*65536;       // slot p-1
    u16* Hcur = (u16*)Hh + (size_t)(p+1)*65536;    // slot p
    bool doG0 = (p < T_);
    bool doG1 = (p >= 1 && p <= T_);
    bool loadG1 = (p >= 1);
    bool doQP = (p >= 2);
    // ---- prefetch X0 gate terms early (hides scattered LLC reads under MFMA) ----
    float x_gi=0.f, x_gf=0.f, x_gg=0.f, x_go=0.f;
    if (doG0 && tid < 128){
      const u16* xr = X0 + ((size_t)p*32 + cb)*4096 + col;
      x_gi = bf2f(xr[0]); x_gf = bf2f(xr[1024]); x_gg = bf2f(xr[2048]); x_go = bf2f(xr[3072]);
    }
    f32x4 acc00={0.f,0.f,0.f,0.f}, acc01={0.f,0.f,0.f,0.f};
    f32x4 acc10={0.f,0.f,0.f,0.f}, acc11={0.f,0.f,0.f,0.f};
    f32x4 accq0={0.f,0.f,0.f,0.f}, accq1={0.f,0.f,0.f,0.f};
    bf16x8 a_g0[2][4], a_g1[2][8];
    // ---- issue ALL A-loads up front (normal cached loads, L2-served broadcast) ----
    if (doG0){
      const u16* a0 = Hprev + (size_t)r*2048 + w*128 + kh*8;
      const u16* a1 = Hprev + (size_t)(16+r)*2048 + w*128 + kh*8;
      #pragma unroll
      for (int kk=0;kk<4;kk++){ a_g0[0][kk] = *(const bf16x8*)(a0 + kk*32);
                                a_g0[1][kk] = *(const bf16x8*)(a1 + kk*32); }
    }
    if (loadG1){
      const u16* a0 = Hprev + (size_t)r*2048 + w*256 + kh*8;
      const u16* a1 = Hprev + (size_t)(16+r)*2048 + w*256 + kh*8;
      #pragma unroll
      for (int kk=0;kk<8;kk++){ a_g1[0][kk] = *(const bf16x8*)(a0 + kk*32);
                                a_g1[1][kk] = *(const bf16x8*)(a1 + kk*32); }
    }
    // ---- MFMA from LDS weights ----
    if (doG0){
      #pragma unroll
      for (int kk=0;kk<4;kk++){
        int c = (w<<4) + (kk<<2) + kh;
        bf16x8 bv = *(const bf16x8*)(W0s + (size_t)((((int)r<<7) + (c ^ (r&7)))*8));
        acc00 = __builtin_amdgcn_mfma_f32_16x16x32_bf16(a_g0[0][kk], bv, acc00, 0,0,0);
        acc01 = __builtin_amdgcn_mfma_f32_16x16x32_bf16(a_g0[1][kk], bv, acc01, 0,0,0);
      }
    }
    if (doG1){
      #pragma unroll
      for (int kk=0;kk<8;kk++){
        int c = (w<<5) + (kk<<2) + kh;
        bf16x8 bv = *(const bf16x8*)(W1s + (size_t)((((int)r<<8) + (c ^ (r&7)))*8));
        acc10 = __builtin_amdgcn_mfma_f32_16x16x32_bf16(a_g1[0][kk], bv, acc10, 0,0,0);
        acc11 = __builtin_amdgcn_mfma_f32_16x16x32_bf16(a_g1[1][kk], bv, acc11, 0,0,0);
      }
    }
    if (doQP && w >= 4){   // qp(p-2) = h1(p-2) @ Wq^T: waves 4-7's a_g1 span K=[1024,2048) = h1
      #pragma unroll
      for (int kk=0;kk<8;kk++){
        int c = ((w-4)<<5) + (kk<<2) + kh;
        int qrw = r & 3;   // only 4 real B rows; cols 4-15 are discarded duplicates
        bf16x8 bv = *(const bf16x8*)(Wqs + (size_t)(((qrw<<7) + (c ^ (qrw&7)))*8));
        accq0 = __builtin_amdgcn_mfma_f32_16x16x32_bf16(a_g1[0][kk], bv, accq0, 0,0,0);
        accq1 = __builtin_amdgcn_mfma_f32_16x16x32_bf16(a_g1[1][kk], bv, accq1, 0,0,0);
      }
    }
    // ---- one-sync cross-wave reduce + cells (stride-17 gl) ----
    #pragma unroll
    for (int rr=0;rr<4;rr++){
      gl0[w*544 + (kh*4+rr)*17 + r]    = acc00[rr];
      gl0[w*544 + (16+kh*4+rr)*17 + r] = acc01[rr];
      gl1[w*544 + (kh*4+rr)*17 + r]    = acc10[rr];
      gl1[w*544 + (16+kh*4+rr)*17 + r] = acc11[rr];
    }
    if (doQP && w >= 4 && r < 4){
      #pragma unroll
      for (int rr=0;rr<4;rr++){
        glq[(w-4)*128 + (kh*4+rr)*4 + r]    = accq0[rr];
        glq[(w-4)*128 + (16+kh*4+rr)*4 + r] = accq1[rr];
      }
    }
    __syncthreads();
    if (tid < 128){
      if (doG0){
        float gi=x_gi, gf=x_gf, gg=x_gg, go=x_go;
        #pragma unroll
        for (int ww=0;ww<8;ww++){
          const float* gp = gl0 + ww*544 + cb*17 + cj;
          gi += gp[0]; gf += gp[4]; gg += gp[8]; go += gp[12];
        }
        float cn = sigm(gf)*c0reg + sigm(gi)*ftanh(gg);
        float hn = sigm(go)*ftanh(cn); c0reg = cn;
        hb0[tid] = f2bf(hn);
      }
      if (doG1){
        float gi=b1i, gf=b1f, gg=b1g, go=b1o;
        #pragma unroll
        for (int ww=0;ww<8;ww++){
          const float* gp = gl1 + ww*544 + cb*17 + cj;
          gi += gp[0]; gf += gp[4]; gg += gp[8]; go += gp[12];
        }
        float cn = sigm(gf)*c1reg + sigm(gi)*ftanh(gg);
        float hn = sigm(go)*ftanh(cn); c1reg = cn;
        hb1[tid] = f2bf(hn);
      }
      if (doQP){
        float hq = glq[cb*4+cj] + glq[128 + cb*4+cj] + glq[256 + cb*4+cj] + glq[384 + cb*4+cj];
        qps[((size_t)(p-2)*32 + cb)*1024 + col] = f2bf(hq);   // plain store; read post-kernel
      }
    }
    __syncthreads();
    // ---- packed coherent h stores + q output (tid<32, one u64 each) ----
    if (tid < 32){
      union { u64 v; u16 s[4]; } pk;
      if (doG0){
        pk.s[0]=hb0[tid*4]; pk.s[1]=hb0[tid*4+1]; pk.s[2]=hb0[tid*4+2]; pk.s[3]=hb0[tid*4+3];
        __hip_atomic_store((u64*)(Hcur + (size_t)tid*2048 + bid*4), pk.v,
                           __ATOMIC_RELAXED, __HIP_MEMORY_SCOPE_AGENT);
      }
      if (doG1){
        pk.s[0]=hb1[tid*4]; pk.s[1]=hb1[tid*4+1]; pk.s[2]=hb1[tid*4+2]; pk.s[3]=hb1[tid*4+3];
        __hip_atomic_store((u64*)(Hcur + (size_t)tid*2048 + 1024 + bid*4), pk.v,
                           __ATOMIC_RELAXED, __HIP_MEMORY_SCOPE_AGENT);
        *(u64*)(qcat + ((size_t)(p-1)*32 + tid)*2048 + bid*4) = pk.v;   // q, normal store
      }
    }
    if (p < T_+1) xcd_barrier(barL, p);
  }
}

// ---------------- persistent attention: 8 blocks/batch x 512 thr, 4 syncs/step ----------------
__global__ __launch_bounds__(512) void k_attn_p(const u16* __restrict__ vpb, const u16* __restrict__ qpb,
    const u16* __restrict__ enc, const float* __restrict__ convw,
    float* __restrict__ eng, u16* __restrict__ qcat, int* __restrict__ barA)
{
  __shared__ float aw[256];
  __shared__ float cred[512];
  int bid = blockIdx.x, tid = threadIdx.x;
  int b = bid>>3, p = bid&7;
  int w = tid>>6, lane = tid&63;
  int d0 = lane*16;
  f32x4 cw[16];
  #pragma unroll
  for (int j=0;j<16;j++) cw[j] = *(const f32x4*)(convw + (size_t)(d0+j)*4);
  if (tid < 256) aw[tid] = 0.f;
  __syncthreads();
  int* cnt = barA + b*32;
  for (int t=0; t<T_; ++t){
    float* ebuf = eng + (t&1)*8192 + b*256;
    // ---- energy: this block covers s in [p*32, p*32+32); wave w does 4 s ----
    const u16* qrow = qpb + ((size_t)t*32 + b)*1024 + d0;
    bf16x8 q0 = *(const bf16x8*)qrow, q1 = *(const bf16x8*)(qrow+8);
    float qf[16];
    #pragma unroll
    for (int j=0;j<16;j++) qf[j] = bf2f((u16)(j<8 ? q0[j] : q1[j-8]));
    #pragma unroll
    for (int ss=0; ss<4; ++ss){
      int s = p*32 + w*4 + ss;
      float am = (s>0)   ? aw[s-1] : 0.f;
      float ac =           aw[s];
      float ap = (s<255) ? aw[s+1] : 0.f;
      const u16* vrow = vpb + ((size_t)(b*256+s))*1024 + d0;
      bf16x8 v0 = *(const bf16x8*)vrow, v1 = *(const bf16x8*)(vrow+8);
      float sum = 0.f;
      #pragma unroll
      for (int j=0;j<16;j++){
        float vv = bf2f((u16)(j<8 ? v0[j] : v1[j-8]));
        float x = qf[j] + vv + am*cw[j][0] + ac*cw[j][1] + ap*cw[j][2];
        sum += ftanh(x)*cw[j][3];
      }
      #pragma unroll
      for (int o=32;o;o>>=1) sum += __shfl_xor(sum, o);
      if (lane==0)
        __hip_atomic_store(ebuf + s, sum, __ATOMIC_RELAXED, __HIP_MEMORY_SCOPE_AGENT);
    }
    ring_barrier(cnt, 8, t);                       // 2 syncs + spin
    // ---- softmax: wave 0 alone, full 256 via 4 vals/lane + in-wave shuffles (0 syncs) ----
    if (w == 0){
      float e0 = __hip_atomic_load(ebuf + lane*4+0, __ATOMIC_RELAXED, __HIP_MEMORY_SCOPE_AGENT);
      float e1 = __hip_atomic_load(ebuf + lane*4+1, __ATOMIC_RELAXED, __HIP_MEMORY_SCOPE_AGENT);
      float e2 = __hip_atomic_load(ebuf + lane*4+2, __ATOMIC_RELAXED, __HIP_MEMORY_SCOPE_AGENT);
      float e3 = __hip_atomic_load(ebuf + lane*4+3, __ATOMIC_RELAXED, __HIP_MEMORY_SCOPE_AGENT);
      float m = fmaxf(fmaxf(e0,e1), fmaxf(e2,e3));
      #pragma unroll
      for (int o=32;o;o>>=1) m = fmaxf(m, __shfl_xor(m,o));
      float x0 = __expf(e0-m), x1 = __expf(e1-m), x2 = __expf(e2-m), x3 = __expf(e3-m);
      float sl = x0+x1+x2+x3;
      #pragma unroll
      for (int o=32;o;o>>=1) sl += __shfl_xor(sl,o);
      float inv = __builtin_amdgcn_rcpf(sl);
      aw[lane*4+0] = x0*inv; aw[lane*4+1] = x1*inv;
      aw[lane*4+2] = x2*inv; aw[lane*4+3] = x3*inv;
    }
    __syncthreads();                               // aw visible (sync 3)
    // ---- context slice d in [p*128, p*128+128): 4-way s-split ----
    int sq = tid>>7, dt = tid&127;
    const u16* ep = enc + (size_t)(b*256 + sq*64)*1024 + p*128 + dt;
    float a0=0.f,a1=0.f,a2=0.f,a3=0.f;
    #pragma unroll 4
    for (int s2=0;s2<64;s2+=4){
      a0 += aw[sq*64+s2]   * bf2f(ep[(size_t)(s2)  *1024]);
      a1 += aw[sq*64+s2+1] * bf2f(ep[(size_t)(s2+1)*1024]);
      a2 += aw[sq*64+s2+2] * bf2f(ep[(size_t)(s2+2)*1024]);
      a3 += aw[sq*64+s2+3] * bf2f(ep[(size_t)(s2+3)*1024]);
    }
    cred[tid] = a0+a1+a2+a3;
    __syncthreads();                               // cred visible (sync 4)
    if (tid < 128)
      qcat[((size_t)t*32 + b)*2048 + 1024 + p*128 + tid] =
        f2bf(cred[tid]+cred[128+tid]+cred[256+tid]+cred[384+tid]);
    // no trailing sync: next energy writes opposite ebuf parity; aw stable until
    // next post-barrier softmax; cred rewritten only after next ring_barrier's syncs.
  }
}

// in-place log_softmax over V per row of out (register-cached, 2 passes of traffic)
__global__ __launch_bounds__(256) void k_logsm(float* __restrict__ out){
  int row = blockIdx.x, tid = threadIdx.x;
  float* p = out + (size_t)row*V_;
  __shared__ float red[4];
  float pv[40];
  int nv = 0;
  float mx = -3.0e38f;
  for (int v=tid; v<V_; v+=256){ float x = p[v]; pv[nv++] = x; mx = fmaxf(mx, x); }
  #pragma unroll
  for (int o=32;o;o>>=1) mx = fmaxf(mx, __shfl_xor(mx,o));
  if ((tid&63)==0) red[tid>>6]=mx;
  __syncthreads();
  mx = fmaxf(fmaxf(red[0],red[1]),fmaxf(red[2],red[3]));
  __syncthreads();
  float s = 0.f;
  for (int i=0;i<nv;i++) s += __expf(pv[i]-mx);
  #pragma unroll
  for (int o=32;o;o>>=1) s += __shfl_xor(s,o);
  if ((tid&63)==0) red[tid>>6]=s;
  __syncthreads();
  float lz = mx + __logf(red[0]+red[1]+red[2]+red[3]);
  { int i=0; for (int v=tid; v<V_; v+=256) p[v] = pv[i++] - lz; }
}

// ---------------- host ----------------
extern "C" void kernel_launch(void* const* d_in, const int* in_sizes, int n_in,
                              void* d_out, int out_size, void* d_ws, size_t ws_size,
                              hipStream_t stream)
{
  const float* enc   = (const float*)d_in[0];
  const int*   tgt   = (const int*)  d_in[1];
  const float* emb   = (const float*)d_in[2];
  const float* Wih   = (const float*)d_in[3];
  const float* Whh   = (const float*)d_in[4];
  const float* bih   = (const float*)d_in[5];
  const float* bhh   = (const float*)d_in[6];
  const float* Wcv   = (const float*)d_in[7];
  const float* bcv   = (const float*)d_in[8];
  const float* Wq    = (const float*)d_in[9];
  const float* Wvm   = (const float*)d_in[10];
  const float* abias = (const float*)d_in[11];
  const float* fcw   = (const float*)d_in[12];
  // d_in[13] fc_attn_b: softmax-invariant, unused
  const float* fc1w  = (const float*)d_in[14];
  const float* fc1b  = (const float*)d_in[15];
  const float* fc2w  = (const float*)d_in[16];
  const float* fc2b  = (const float*)d_in[17];
  float* out = (float*)d_out;

  char* base = (char*)d_ws; size_t off = 0;
  auto A = [&](size_t nbytes)->char*{ char* q = base + off; off += (nbytes + 255) & ~(size_t)255; return q; };
  u16* enc_bf  = (u16*)A(8388608ull*2);
  u16* Wv_bf   = (u16*)A(1048576ull*2);
  u16* Wih0_bf = (u16*)A(4194304ull*2);
  u16* W1cat   = (u16*)A(8388608ull*2);
  u16* Whh0_bf = (u16*)A(4194304ull*2);
  u16* Wq_bf   = (u16*)A(1048576ull*2);
  u16* fc1w_bf = (u16*)A(2097152ull*2);
  u16* fc2w_bf = (u16*)A(10240000ull*2);  // ALSO aliased as Hh during the LSTM phase
  u16* embA    = (u16*)A(4194304ull*2);   // reused: X0-GEMM A -> qps -> hid
  u16* X0      = (u16*)A(16777216ull*2);  // (T*32, 4096) bf16, includes bias0
  u16* vpb     = (u16*)A(8388608ull*2);   // bf16(vproj + bconv + attn_bias)
  u16* qcat    = (u16*)A(8388608ull*2);   // (T*32, 2048) = [q | context]
  float* bias0 = (float*)A(4096*4);
  float* bias1 = (float*)A(4096*4);
  float* biasE = (float*)A(1024*4);
  float* convw = (float*)A(4096*4);       // [d][{Wc0,Wc1,Wc2,fcw}]
  float* eng   = (float*)A(2*8192*4);     // attn energy double buffer
  int* barL    = (int*)A(4096);           // hierarchical barrier, 128B-padded lines
  int* barA    = (int*)A(4096);           // 32 batches x 32-int (128B) lines
  u16* Hh      = fc2w_bf;                 // 131 slots x (32x2048) bf16 = 17.2 MB <= 20.48 MB
  u16* qps     = embA;                    // (T*32, 1024) bf16 qp (embA free after X0 GEMM)
  u16* hid     = embA;

  // zero h-history slots -1 and 0 + barriers (re-done on every graph replay)
  hipMemsetAsync(Hh, 0, 2*65536*2, stream);
  hipMemsetAsync(barL, 0, 4096, stream);
  hipMemsetAsync(barA, 0, 4096, stream);

  // prep: bf16 casts (fc2w cast DEFERRED until after LSTM+attn; its buffer holds Hh now)
  k_cast<<<2048,256,0,stream>>>(enc,  enc_bf,  8388608);
  k_cast<<<1024,256,0,stream>>>(Wih,  Wih0_bf, 4194304);
  k_cast<<<1024,256,0,stream>>>(Whh,  Whh0_bf, 4194304);
  k_cast<<<512,256,0,stream>>>(Wq,    Wq_bf,   1048576);
  k_cast<<<512,256,0,stream>>>(Wvm,   Wv_bf,   1048576);
  k_cast<<<512,256,0,stream>>>(fc1w,  fc1w_bf, 2097152);
  k_w1cat<<<2048,256,0,stream>>>(Wih + 4194304, Whh + 4194304, W1cat);
  k_bias<<<16,256,0,stream>>>(bih, bhh, bcv, abias, Wcv, fcw, bias0, bias1, biasE, convw);
  k_gather<<<4096,256,0,stream>>>(emb, tgt, embA);

  // vpb = bf16(enc @ Wv^T + (bconv + attn_bias))   (8192 x 1024 x 1024)
  k_gemm128<1,false><<<dim3(8,64),256,0,stream>>>(enc_bf, Wv_bf, biasE, vpb, 8192, 1024, 1024, 1024, 1024);
  // X0 = bf16(emb[targets] @ W_ih0^T + (b_ih0+b_hh0))  (4096 x 4096 x 1024)
  k_gemm128<1,false><<<dim3(32,32),256,0,stream>>>(embA, Wih0_bf, bias0, X0, 4096, 4096, 1024, 1024, 4096);

  // ---- persistent LSTM loop (256 blocks, weights in LDS, folded qp, hierarchical barrier) ----
  {
    const u16* a0 = Whh0_bf; const u16* a1 = W1cat; const u16* a2 = Wq_bf; const u16* a3 = X0;
    const float* a4 = bias1; u16* a5 = Hh; u16* a6 = qcat; u16* a7 = qps; int* a8 = barL;
    void* args[] = {(void*)&a0,(void*)&a1,(void*)&a2,(void*)&a3,(void*)&a4,(void*)&a5,
                    (void*)&a6,(void*)&a7,(void*)&a8};
    hipError_t e = hipLaunchCooperativeKernel((const void*)k_lstm_p, dim3(256), dim3(512), args, 0, stream);
    if (e != hipSuccess)
      k_lstm_p<<<dim3(256),dim3(512),0,stream>>>(a0,a1,a2,a3,a4,a5,a6,a7,a8);
  }

  // ---- persistent attention loop (256 blocks x 512 thr, per-batch barrier) ----
  {
    const u16* a0 = vpb; const u16* a1 = qps; const u16* a2 = enc_bf; const float* a3 = convw;
    float* a4 = eng; u16* a5 = qcat; int* a6 = barA;
    void* args[] = {(void*)&a0,(void*)&a1,(void*)&a2,(void*)&a3,(void*)&a4,(void*)&a5,(void*)&a6};
    hipError_t e = hipLaunchCooperativeKernel((const void*)k_attn_p, dim3(256), dim3(512), args, 0, stream);
    if (e != hipSuccess)
      k_attn_p<<<dim3(256),dim3(512),0,stream>>>(a0,a1,a2,a3,a4,a5,a6);
  }

  // hid = tanh(qcat @ fc1w^T + fc1b)   (4096 x 1024 x 2048)
  k_gemm128<2,false><<<dim3(8,32),256,0,stream>>>(qcat, fc1w_bf, fc1b, hid, 4096, 1024, 2048, 2048, 1024);
  // fc2 weight cast (deferred; Hh no longer needed)
  k_cast<<<2048,256,0,stream>>>(fc2w, fc2w_bf, 10240000);
  // logits = hid @ fc2w^T + fc2b -> out[b][t][v]  (4096 x 10000 x 1024, row swizzle (t,b)->(b,t))
  k_gemm128<0,true><<<dim3(79,32),256,0,stream>>>(hid, fc2w_bf, fc2b, out, 4096, V_, 1024, 1024, V_);
  // in-place log_softmax over V
  k_logsm<<<4096,256,0,stream>>>(out);
}